// Round 1
// baseline (6040.891 us; speedup 1.0000x reference)
//
#include <hip/hip_runtime.h>
#include <hip/hip_bf16.h>
#include <stdint.h>
#include <stddef.h>

#define SEQ   512
#define BATCH 64
#define NIN   1024
#define NHID  1024
#define NG    4096   // 4*NHID

typedef __attribute__((ext_vector_type(8))) short bf16x8;
typedef __attribute__((ext_vector_type(4))) float f32x4;

static __device__ __forceinline__ ushort f2bf(float f) {
  uint32_t u = __builtin_bit_cast(uint32_t, f);
  uint32_t lsb = (u >> 16) & 1u;
  u += 0x7fffu + lsb;           // round-to-nearest-even
  return (ushort)(u >> 16);
}

static __device__ __forceinline__ f32x4 mfma_bf16(bf16x8 a, bf16x8 b, f32x4 c) {
  return __builtin_amdgcn_mfma_f32_16x16x32_bf16(a, b, c, 0, 0, 0);
}

static __device__ __forceinline__ void lds_load16(const ushort* g, ushort* l) {
  __builtin_amdgcn_global_load_lds(
      (const __attribute__((address_space(1))) void*)g,
      (__attribute__((address_space(3))) void*)l, 16, 0, 0);
}

// ---------------- converts ----------------

__global__ __launch_bounds__(256) void k_convert_x(const float* __restrict__ X,
                                                   ushort* __restrict__ Xb, int n4) {
  int i = blockIdx.x * 256 + threadIdx.x;
  if (i < n4) {
    float4 v = ((const float4*)X)[i];
    ushort4 o;
    o.x = f2bf(v.x); o.y = f2bf(v.y); o.z = f2bf(v.z); o.w = f2bf(v.w);
    ((ushort4*)Xb)[i] = o;
  }
}

// permuted row order: p = cg*64 + g*16 + j  <->  r = g*1024 + cg*16 + j
__global__ __launch_bounds__(256) void k_convert_w(const float* __restrict__ W,
                                                   const float* __restrict__ bvec,
                                                   ushort* __restrict__ Wxb,
                                                   ushort* __restrict__ Whb,
                                                   float* __restrict__ bp) {
  int p = blockIdx.x;
  int cg = p >> 6, g = (p >> 4) & 3, j = p & 15;
  int r = g * 1024 + cg * 16 + j;
  const float* src = W + (size_t)r * 2048;
  for (int k4 = threadIdx.x; k4 < 512; k4 += 256) {
    float4 v = ((const float4*)src)[k4];
    ushort4 o;
    o.x = f2bf(v.x); o.y = f2bf(v.y); o.z = f2bf(v.z); o.w = f2bf(v.w);
    if (k4 < 256) ((ushort4*)(Wxb + (size_t)p * 1024))[k4] = o;
    else          ((ushort4*)(Whb + (size_t)p * 1024))[k4 - 256] = o;
  }
  if (threadIdx.x == 0) bp[p] = bvec[r];
}

__global__ __launch_bounds__(256) void k_zero(ushort* __restrict__ hb0,
                                              ushort* __restrict__ hb1,
                                              float* __restrict__ cst) {
  int i = blockIdx.x * 256 + threadIdx.x;  // 65536 total
  hb0[i] = 0; hb1[i] = 0; cst[i] = 0.f;
}

// ---------------- GEMM1: Ax[m][p] = sum_k Xb[m][k]*Wxb[p][k] + bp[p] ----------------
// 128x128 tile, BK=32, 4 waves (2x2 of 64x64)

__global__ __launch_bounds__(256) void k_gemm1(const ushort* __restrict__ Xb,
                                               const ushort* __restrict__ Wxb,
                                               const float* __restrict__ bp,
                                               float* __restrict__ Ax) {
  __shared__ ushort As[128 * 32];
  __shared__ ushort Bs[128 * 32];
  const int m0 = blockIdx.x * 128;
  const int n0 = blockIdx.y * 128;
  const int tid = threadIdx.x;
  const int w = tid >> 6, l = tid & 63;
  const int wr = w >> 1, wc = w & 1;
  const int lr = l >> 2;          // row within 16-row chunk
  const int lc = (l & 3) * 8;     // elem col within 32
  const int fr = l & 15, fk8 = (l >> 4) * 8, fq = l >> 4;

  f32x4 acc[4][4] = {};

  for (int kb = 0; kb < 1024; kb += 32) {
    // stage A+B: 8 chunks of 1KB each; wave w takes chunks {w, w+4}
    lds_load16(Xb  + (size_t)(m0 + w * 16 + lr) * 1024 + kb + lc,       &As[w * 512]);
    lds_load16(Xb  + (size_t)(m0 + (w + 4) * 16 + lr) * 1024 + kb + lc, &As[(w + 4) * 512]);
    lds_load16(Wxb + (size_t)(n0 + w * 16 + lr) * 1024 + kb + lc,       &Bs[w * 512]);
    lds_load16(Wxb + (size_t)(n0 + (w + 4) * 16 + lr) * 1024 + kb + lc, &Bs[(w + 4) * 512]);
    __syncthreads();
    bf16x8 af[4], bfr[4];
#pragma unroll
    for (int i = 0; i < 4; i++) af[i]  = *(const bf16x8*)&As[(wr * 64 + i * 16 + fr) * 32 + fk8];
#pragma unroll
    for (int i = 0; i < 4; i++) bfr[i] = *(const bf16x8*)&Bs[(wc * 64 + i * 16 + fr) * 32 + fk8];
#pragma unroll
    for (int i = 0; i < 4; i++)
#pragma unroll
      for (int jj = 0; jj < 4; jj++)
        acc[i][jj] = mfma_bf16(af[i], bfr[jj], acc[i][jj]);
    __syncthreads();
  }

#pragma unroll
  for (int jj = 0; jj < 4; jj++) {
    int gc = n0 + wc * 64 + jj * 16 + fr;
    float bb = bp[gc];
#pragma unroll
    for (int i = 0; i < 4; i++) {
      int grb = m0 + wr * 64 + i * 16 + fq * 4;
#pragma unroll
      for (int jr = 0; jr < 4; jr++)
        Ax[(size_t)(grb + jr) * NG + gc] = acc[i][jj][jr] + bb;
    }
  }
}

// ---------------- recurrent step ----------------
// grid 256 = 64 colgroups x 4 batchgroups; 4 waves split K.
// MODE 0: K=1024 over h, add Ax (bias folded in).  MODE 1: K=2048 over [x,h], add bp.

template <int MODE>
__global__ __launch_bounds__(256) void k_step(int t,
                                              const ushort* __restrict__ Xb,
                                              const ushort* __restrict__ Wxb,
                                              const ushort* __restrict__ Whb,
                                              const float* __restrict__ bp,
                                              const float* __restrict__ Ax,
                                              const ushort* __restrict__ hprev,
                                              ushort* __restrict__ hnext,
                                              float* __restrict__ cst,
                                              float* __restrict__ out) {
  __shared__ float red[4][16][64];
  const int bidx = blockIdx.x;
  const int cg = bidx & 63, mb = bidx >> 6;
  const int b0 = mb * 16, pcol = cg * 64;
  const int tid = threadIdx.x, w = tid >> 6, l = tid & 63;
  const int fr = l & 15, fk8 = (l >> 4) * 8, fq = l >> 4;

  f32x4 acc[4] = {};

  const ushort* aSrc;
  const ushort* bMat;
  int kbase;
  if (MODE == 0) {
    aSrc = hprev + (size_t)(b0 + fr) * 1024 + w * 256 + fk8;
    bMat = Whb; kbase = w * 256;
  } else {
    if (w < 2) { aSrc = Xb + (size_t)(t * 64 + b0 + fr) * 1024 + w * 512 + fk8; bMat = Wxb; kbase = w * 512; }
    else       { aSrc = hprev + (size_t)(b0 + fr) * 1024 + (w - 2) * 512 + fk8; bMat = Whb; kbase = (w - 2) * 512; }
  }
  const ushort* bRow = bMat + (size_t)(pcol + fr) * 1024 + kbase + fk8;
  const int ksteps = (MODE == 0) ? 8 : 16;

#pragma unroll
  for (int ks = 0; ks < ((MODE == 0) ? 8 : 16); ks++) {
    int kk = ks * 32;
    bf16x8 a = *(const bf16x8*)(aSrc + kk);
#pragma unroll
    for (int bj = 0; bj < 4; bj++) {
      bf16x8 bfv = *(const bf16x8*)(bRow + (size_t)bj * 16 * 1024 + kk);
      acc[bj] = mfma_bf16(a, bfv, acc[bj]);
    }
  }
  (void)ksteps;

#pragma unroll
  for (int bj = 0; bj < 4; bj++)
#pragma unroll
    for (int jr = 0; jr < 4; jr++)
      red[w][fq * 4 + jr][bj * 16 + fr] = acc[bj][jr];
  __syncthreads();

  const int b = tid >> 4, j = tid & 15;
  float ai_ = 0.f, af_ = 0.f, ao_ = 0.f, ag_ = 0.f;
#pragma unroll
  for (int ww = 0; ww < 4; ww++) {
    ai_ += red[ww][b][j];
    af_ += red[ww][b][16 + j];
    ao_ += red[ww][b][32 + j];
    ag_ += red[ww][b][48 + j];
  }
  if (MODE == 0) {
    const float* axp = Ax + (size_t)(t * 64 + b0 + b) * NG + pcol;
    ai_ += axp[j]; af_ += axp[16 + j]; ao_ += axp[32 + j]; ag_ += axp[48 + j];
  } else {
    ai_ += bp[pcol + j]; af_ += bp[pcol + 16 + j]; ao_ += bp[pcol + 32 + j]; ag_ += bp[pcol + 48 + j];
  }
  float ig = 1.f / (1.f + __expf(-ai_));
  float fg = 1.f / (1.f + __expf(-af_));
  float og = 1.f / (1.f + __expf(-ao_));
  float gg = tanhf(ag_);
  int hidx = (b0 + b) * 1024 + cg * 16 + j;
  float cn = cst[hidx] * fg + ig * gg;
  cst[hidx] = cn;
  float h = og * tanhf(cn);
  out[(size_t)t * 65536 + hidx] = h;
  hnext[hidx] = f2bf(h);
  if (t == SEQ - 1) out[(size_t)SEQ * 65536 + hidx] = h;
}

// ---------------- host ----------------

extern "C" void kernel_launch(void* const* d_in, const int* in_sizes, int n_in,
                              void* d_out, int out_size, void* d_ws, size_t ws_size,
                              hipStream_t stream) {
  const float* X    = (const float*)d_in[0];
  const float* W    = (const float*)d_in[1];
  const float* bvec = (const float*)d_in[2];
  float* out = (float*)d_out;
  char* ws = (char*)d_ws;

  size_t off = 0;
  auto alloc = [&](size_t bytes) -> char* {
    char* p = ws + off;
    off += (bytes + 255) & ~(size_t)255;
    return p;
  };
  ushort* Xb  = (ushort*)alloc((size_t)SEQ * BATCH * NIN * 2);
  ushort* Wxb = (ushort*)alloc((size_t)NG * NIN * 2);
  ushort* Whb = (ushort*)alloc((size_t)NG * NHID * 2);
  float*  bp  = (float*)alloc((size_t)NG * 4);
  ushort* hb0 = (ushort*)alloc((size_t)BATCH * NHID * 2);
  ushort* hb1 = (ushort*)alloc((size_t)BATCH * NHID * 2);
  float*  cst = (float*)alloc((size_t)BATCH * NHID * 4);
  size_t base_need = off;
  float*  Ax  = (float*)alloc((size_t)SEQ * BATCH * NG * 4);
  size_t fast_need = off;

  if (ws_size < base_need) return;  // cannot run at all
  const bool fast = (ws_size >= fast_need);

  k_convert_x<<<(SEQ * BATCH * NIN / 4 + 255) / 256, 256, 0, stream>>>(X, Xb, SEQ * BATCH * NIN / 4);
  k_convert_w<<<NG, 256, 0, stream>>>(W, bvec, Wxb, Whb, bp);
  k_zero<<<BATCH * NHID / 256, 256, 0, stream>>>(hb0, hb1, cst);

  if (fast) {
    k_gemm1<<<dim3(SEQ * BATCH / 128, NG / 128), 256, 0, stream>>>(Xb, Wxb, bp, Ax);
    for (int t = 0; t < SEQ; t++) {
      const ushort* hp = (t & 1) ? hb1 : hb0;
      ushort*       hn = (t & 1) ? hb0 : hb1;
      k_step<0><<<256, 256, 0, stream>>>(t, Xb, Wxb, Whb, bp, Ax, hp, hn, cst, out);
    }
  } else {
    for (int t = 0; t < SEQ; t++) {
      const ushort* hp = (t & 1) ? hb1 : hb0;
      ushort*       hn = (t & 1) ? hb0 : hb1;
      k_step<1><<<256, 256, 0, stream>>>(t, Xb, Wxb, Whb, bp, Ax, hp, hn, cst, out);
    }
  }
}

// Round 2
// 6031.175 us; speedup vs baseline: 1.0016x; 1.0016x over previous
//
#include <hip/hip_runtime.h>
#include <hip/hip_bf16.h>
#include <stdint.h>
#include <stddef.h>

#define SEQ   512
#define BATCH 64
#define NIN   1024
#define NHID  1024
#define NG    4096   // 4*NHID

typedef __attribute__((ext_vector_type(8))) short bf16x8;
typedef __attribute__((ext_vector_type(4))) float f32x4;

static __device__ __forceinline__ ushort f2bf(float f) {
  uint32_t u = __builtin_bit_cast(uint32_t, f);
  uint32_t lsb = (u >> 16) & 1u;
  u += 0x7fffu + lsb;           // round-to-nearest-even
  return (ushort)(u >> 16);
}

static __device__ __forceinline__ f32x4 mfma_bf16(bf16x8 a, bf16x8 b, f32x4 c) {
  return __builtin_amdgcn_mfma_f32_16x16x32_bf16(a, b, c, 0, 0, 0);
}

static __device__ __forceinline__ void lds_load16(const ushort* g, ushort* l) {
  __builtin_amdgcn_global_load_lds(
      (const __attribute__((address_space(1))) void*)g,
      (__attribute__((address_space(3))) void*)l, 16, 0, 0);
}

// ---------------- converts ----------------

__global__ __launch_bounds__(256) void k_convert_x(const float* __restrict__ X,
                                                   ushort* __restrict__ Xb, int n4) {
  int i = blockIdx.x * 256 + threadIdx.x;
  if (i < n4) {
    float4 v = ((const float4*)X)[i];
    ushort4 o;
    o.x = f2bf(v.x); o.y = f2bf(v.y); o.z = f2bf(v.z); o.w = f2bf(v.w);
    ((ushort4*)Xb)[i] = o;
  }
}

// permuted row order: p = cg*64 + g*16 + j  <->  r = g*1024 + cg*16 + j
__global__ __launch_bounds__(256) void k_convert_w(const float* __restrict__ W,
                                                   const float* __restrict__ bvec,
                                                   ushort* __restrict__ Wxb,
                                                   ushort* __restrict__ Whb,
                                                   float* __restrict__ bp) {
  int p = blockIdx.x;
  int cg = p >> 6, g = (p >> 4) & 3, j = p & 15;
  int r = g * 1024 + cg * 16 + j;
  const float* src = W + (size_t)r * 2048;
  for (int k4 = threadIdx.x; k4 < 512; k4 += 256) {
    float4 v = ((const float4*)src)[k4];
    ushort4 o;
    o.x = f2bf(v.x); o.y = f2bf(v.y); o.z = f2bf(v.z); o.w = f2bf(v.w);
    if (k4 < 256) ((ushort4*)(Wxb + (size_t)p * 1024))[k4] = o;
    else          ((ushort4*)(Whb + (size_t)p * 1024))[k4 - 256] = o;
  }
  if (threadIdx.x == 0) bp[p] = bvec[r];
}

__global__ __launch_bounds__(256) void k_zero(ushort* __restrict__ hb0,
                                              ushort* __restrict__ hb1,
                                              float* __restrict__ cst,
                                              uint32_t* __restrict__ flags) {
  int i = blockIdx.x * 256 + threadIdx.x;  // 65536 total
  hb0[i] = 0; hb1[i] = 0; cst[i] = 0.f;
  if (blockIdx.x == 0) flags[threadIdx.x] = 0;
}

// ---------------- GEMM1: Ax[m][p] = sum_k Xb[m][k]*Wxb[p][k] + bp[p] ----------------
// 128x128 tile, BK=32, 4 waves (2x2 of 64x64)

__global__ __launch_bounds__(256) void k_gemm1(const ushort* __restrict__ Xb,
                                               const ushort* __restrict__ Wxb,
                                               const float* __restrict__ bp,
                                               float* __restrict__ Ax) {
  __shared__ ushort As[128 * 32];
  __shared__ ushort Bs[128 * 32];
  const int m0 = blockIdx.x * 128;
  const int n0 = blockIdx.y * 128;
  const int tid = threadIdx.x;
  const int w = tid >> 6, l = tid & 63;
  const int wr = w >> 1, wc = w & 1;
  const int lr = l >> 2;          // row within 16-row chunk
  const int lc = (l & 3) * 8;     // elem col within 32
  const int fr = l & 15, fk8 = (l >> 4) * 8, fq = l >> 4;

  f32x4 acc[4][4] = {};

  for (int kb = 0; kb < 1024; kb += 32) {
    lds_load16(Xb  + (size_t)(m0 + w * 16 + lr) * 1024 + kb + lc,       &As[w * 512]);
    lds_load16(Xb  + (size_t)(m0 + (w + 4) * 16 + lr) * 1024 + kb + lc, &As[(w + 4) * 512]);
    lds_load16(Wxb + (size_t)(n0 + w * 16 + lr) * 1024 + kb + lc,       &Bs[w * 512]);
    lds_load16(Wxb + (size_t)(n0 + (w + 4) * 16 + lr) * 1024 + kb + lc, &Bs[(w + 4) * 512]);
    __syncthreads();
    bf16x8 af[4], bfr[4];
#pragma unroll
    for (int i = 0; i < 4; i++) af[i]  = *(const bf16x8*)&As[(wr * 64 + i * 16 + fr) * 32 + fk8];
#pragma unroll
    for (int i = 0; i < 4; i++) bfr[i] = *(const bf16x8*)&Bs[(wc * 64 + i * 16 + fr) * 32 + fk8];
#pragma unroll
    for (int i = 0; i < 4; i++)
#pragma unroll
      for (int jj = 0; jj < 4; jj++)
        acc[i][jj] = mfma_bf16(af[i], bfr[jj], acc[i][jj]);
    __syncthreads();
  }

#pragma unroll
  for (int jj = 0; jj < 4; jj++) {
    int gc = n0 + wc * 64 + jj * 16 + fr;
    float bb = bp[gc];
#pragma unroll
    for (int i = 0; i < 4; i++) {
      int grb = m0 + wr * 64 + i * 16 + fq * 4;
#pragma unroll
      for (int jr = 0; jr < 4; jr++)
        Ax[(size_t)(grb + jr) * NG + gc] = acc[i][jj][jr] + bb;
    }
  }
}

// ---------------- persistent recurrence (cooperative) ----------------
// grid 256 = 4 teams x 64 hidden-groups. Team t owns batches [t*16,+16), runs
// independently. Block hg owns h-cols [hg*16,+16) = permuted gate cols
// [hg*64,+64). Wh slice (64x1024 bf16 = 128KB) LDS-resident, XOR-swizzled.
// c state: 1 float per thread (registers). Team barrier: leaderless monotonic
// epoch flags, agent-scope atomics + device fences for cross-XCD visibility.

__global__ __launch_bounds__(256) void k_persist(const ushort* __restrict__ Whb,
                                                 const float* __restrict__ Ax,
                                                 ushort* __restrict__ hb0,
                                                 ushort* __restrict__ hb1,
                                                 float* __restrict__ out,
                                                 uint32_t* __restrict__ flags) {
  __shared__ ushort Wsh[64 * 1024];      // 128 KB
  __shared__ float red[4][16][64];       // 16 KB

  const int bid = blockIdx.x;
  const int team = bid >> 6, hg = bid & 63;
  const int tid = threadIdx.x, w = tid >> 6, l = tid & 63;
  const int fr = l & 15, fq = l >> 4, fk8 = fq * 8;
  const int xm = (fr & 7) << 3;          // per-lane LDS XOR mask (elem units)

  // ---- stage Wh slice into LDS (once), swizzled ----
  {
    const ushort* wsrc = Whb + (size_t)(hg * 64) * 1024;
    for (int it = 0; it < 32; ++it) {
      int idx = it * 256 + tid;          // 8192 chunks of 8 elems
      int row = idx >> 7, c8 = idx & 127;
      bf16x8 v = *(const bf16x8*)(wsrc + (size_t)row * 1024 + c8 * 8);
      int col = (c8 * 8) ^ ((row & 7) << 3);
      *(bf16x8*)&Wsh[row * 1024 + col] = v;
    }
  }
  __syncthreads();

  const int eb = tid >> 4, ej = tid & 15;  // epilogue: batch-in-team, hcol-in-group
  float creg = 0.f;

  uint32_t* myflag = flags + bid;
  uint32_t* tflags = flags + team * 64;

  for (int t = 0; t < SEQ; ++t) {
    const ushort* hb_r = (t & 1) ? hb1 : hb0;
    ushort*       hb_w = (t & 1) ? hb0 : hb1;

    if (t > 0) {
      if (w == 0) {
        while (true) {
          uint32_t v = __hip_atomic_load(&tflags[l], __ATOMIC_RELAXED,
                                         __HIP_MEMORY_SCOPE_AGENT);
          if (__all((int)(v >= (uint32_t)t))) break;
          __builtin_amdgcn_s_sleep(1);
        }
        __threadfence();  // acquire: invalidate stale L1/L2 before h reads
      }
      __syncthreads();
    }

    // ---- MFMA: gates[16b x 64p] over K=1024, split 4 ways across waves ----
    const ushort* aSrc = hb_r + (size_t)(team * 16 + fr) * 1024 + w * 256 + fk8;
    f32x4 acc[4] = {};
#pragma unroll
    for (int ks = 0; ks < 8; ++ks) {
      bf16x8 a = *(const bf16x8*)(aSrc + ks * 32);
#pragma unroll
      for (int bj = 0; bj < 4; ++bj) {
        int row = bj * 16 + fr;
        int col = (w * 256 + ks * 32 + fk8) ^ xm;
        bf16x8 bv = *(const bf16x8*)&Wsh[row * 1024 + col];
        acc[bj] = mfma_bf16(a, bv, acc[bj]);
      }
    }

#pragma unroll
    for (int bj = 0; bj < 4; ++bj)
#pragma unroll
      for (int jr = 0; jr < 4; ++jr)
        red[w][fq * 4 + jr][bj * 16 + fr] = acc[bj][jr];
    __syncthreads();

    // ---- epilogue: one (batch, hcol) per thread ----
    float ai_ = 0.f, af_ = 0.f, ao_ = 0.f, ag_ = 0.f;
#pragma unroll
    for (int ww = 0; ww < 4; ++ww) {
      ai_ += red[ww][eb][ej];
      af_ += red[ww][eb][16 + ej];
      ao_ += red[ww][eb][32 + ej];
      ag_ += red[ww][eb][48 + ej];
    }
    const float* axp = Ax + ((size_t)t * 64 + team * 16 + eb) * NG + hg * 64;
    ai_ += axp[ej]; af_ += axp[16 + ej]; ao_ += axp[32 + ej]; ag_ += axp[48 + ej];

    float ig = 1.f / (1.f + __expf(-ai_));
    float fg = 1.f / (1.f + __expf(-af_));
    float og = 1.f / (1.f + __expf(-ao_));
    float gg = tanhf(ag_);
    creg = creg * fg + ig * gg;
    float h = og * tanhf(creg);
    int hidx = (team * 16 + eb) * 1024 + hg * 16 + ej;
    out[(size_t)t * 65536 + hidx] = h;
    hb_w[hidx] = f2bf(h);
    if (t == SEQ - 1) out[(size_t)SEQ * 65536 + hidx] = h;

    // ---- publish: all block stores drained (syncthreads), then fence+flag ----
    __syncthreads();
    if (tid == 0) {
      __threadfence();  // release: push h stores past local L2
      __hip_atomic_store(myflag, (uint32_t)(t + 1), __ATOMIC_RELAXED,
                         __HIP_MEMORY_SCOPE_AGENT);
    }
  }
}

// ---------------- fallback per-step kernel (round 1) ----------------

template <int MODE>
__global__ __launch_bounds__(256) void k_step(int t,
                                              const ushort* __restrict__ Xb,
                                              const ushort* __restrict__ Wxb,
                                              const ushort* __restrict__ Whb,
                                              const float* __restrict__ bp,
                                              const float* __restrict__ Ax,
                                              const ushort* __restrict__ hprev,
                                              ushort* __restrict__ hnext,
                                              float* __restrict__ cst,
                                              float* __restrict__ out) {
  __shared__ float red[4][16][64];
  const int bidx = blockIdx.x;
  const int cg = bidx & 63, mb = bidx >> 6;
  const int b0 = mb * 16, pcol = cg * 64;
  const int tid = threadIdx.x, w = tid >> 6, l = tid & 63;
  const int fr = l & 15, fk8 = (l >> 4) * 8, fq = l >> 4;

  f32x4 acc[4] = {};

  const ushort* aSrc;
  const ushort* bMat;
  int kbase;
  if (MODE == 0) {
    aSrc = hprev + (size_t)(b0 + fr) * 1024 + w * 256 + fk8;
    bMat = Whb; kbase = w * 256;
  } else {
    if (w < 2) { aSrc = Xb + (size_t)(t * 64 + b0 + fr) * 1024 + w * 512 + fk8; bMat = Wxb; kbase = w * 512; }
    else       { aSrc = hprev + (size_t)(b0 + fr) * 1024 + (w - 2) * 512 + fk8; bMat = Whb; kbase = (w - 2) * 512; }
  }
  const ushort* bRow = bMat + (size_t)(pcol + fr) * 1024 + kbase + fk8;

#pragma unroll
  for (int ks = 0; ks < ((MODE == 0) ? 8 : 16); ks++) {
    int kk = ks * 32;
    bf16x8 a = *(const bf16x8*)(aSrc + kk);
#pragma unroll
    for (int bj = 0; bj < 4; bj++) {
      bf16x8 bfv = *(const bf16x8*)(bRow + (size_t)bj * 16 * 1024 + kk);
      acc[bj] = mfma_bf16(a, bfv, acc[bj]);
    }
  }

#pragma unroll
  for (int bj = 0; bj < 4; bj++)
#pragma unroll
    for (int jr = 0; jr < 4; jr++)
      red[w][fq * 4 + jr][bj * 16 + fr] = acc[bj][jr];
  __syncthreads();

  const int b = tid >> 4, j = tid & 15;
  float ai_ = 0.f, af_ = 0.f, ao_ = 0.f, ag_ = 0.f;
#pragma unroll
  for (int ww = 0; ww < 4; ww++) {
    ai_ += red[ww][b][j];
    af_ += red[ww][b][16 + j];
    ao_ += red[ww][b][32 + j];
    ag_ += red[ww][b][48 + j];
  }
  if (MODE == 0) {
    const float* axp = Ax + (size_t)(t * 64 + b0 + b) * NG + pcol;
    ai_ += axp[j]; af_ += axp[16 + j]; ao_ += axp[32 + j]; ag_ += axp[48 + j];
  } else {
    ai_ += bp[pcol + j]; af_ += bp[pcol + 16 + j]; ao_ += bp[pcol + 32 + j]; ag_ += bp[pcol + 48 + j];
  }
  float ig = 1.f / (1.f + __expf(-ai_));
  float fg = 1.f / (1.f + __expf(-af_));
  float og = 1.f / (1.f + __expf(-ao_));
  float gg = tanhf(ag_);
  int hidx = (b0 + b) * 1024 + cg * 16 + j;
  float cn = cst[hidx] * fg + ig * gg;
  cst[hidx] = cn;
  float h = og * tanhf(cn);
  out[(size_t)t * 65536 + hidx] = h;
  hnext[hidx] = f2bf(h);
  if (t == SEQ - 1) out[(size_t)SEQ * 65536 + hidx] = h;
}

// ---------------- host ----------------

extern "C" void kernel_launch(void* const* d_in, const int* in_sizes, int n_in,
                              void* d_out, int out_size, void* d_ws, size_t ws_size,
                              hipStream_t stream) {
  const float* X    = (const float*)d_in[0];
  const float* W    = (const float*)d_in[1];
  const float* bvec = (const float*)d_in[2];
  float* out = (float*)d_out;
  char* ws = (char*)d_ws;

  size_t off = 0;
  auto alloc = [&](size_t bytes) -> char* {
    char* p = ws + off;
    off += (bytes + 255) & ~(size_t)255;
    return p;
  };
  ushort* Xb    = (ushort*)alloc((size_t)SEQ * BATCH * NIN * 2);
  ushort* Wxb   = (ushort*)alloc((size_t)NG * NIN * 2);
  ushort* Whb   = (ushort*)alloc((size_t)NG * NHID * 2);
  float*  bp    = (float*)alloc((size_t)NG * 4);
  ushort* hb0   = (ushort*)alloc((size_t)BATCH * NHID * 2);
  ushort* hb1   = (ushort*)alloc((size_t)BATCH * NHID * 2);
  float*  cst   = (float*)alloc((size_t)BATCH * NHID * 4);
  uint32_t* flg = (uint32_t*)alloc(256 * 4);
  size_t base_need = off;
  float*  Ax  = (float*)alloc((size_t)SEQ * BATCH * NG * 4);
  size_t fast_need = off;

  if (ws_size < base_need) return;
  const bool fast = (ws_size >= fast_need);

  k_convert_x<<<(SEQ * BATCH * NIN / 4 + 255) / 256, 256, 0, stream>>>(X, Xb, SEQ * BATCH * NIN / 4);
  k_convert_w<<<NG, 256, 0, stream>>>(W, bvec, Wxb, Whb, bp);
  k_zero<<<BATCH * NHID / 256, 256, 0, stream>>>(hb0, hb1, cst, flg);

  bool done = false;
  if (fast) {
    k_gemm1<<<dim3(SEQ * BATCH / 128, NG / 128), 256, 0, stream>>>(Xb, Wxb, bp, Ax);
    void* args[] = {(void*)&Whb, (void*)&Ax, (void*)&hb0, (void*)&hb1,
                    (void*)&out, (void*)&flg};
    hipError_t e = hipLaunchCooperativeKernel((const void*)k_persist,
                                              dim3(256), dim3(256), args, 0, stream);
    if (e == hipSuccess) {
      done = true;
    } else {
      (void)hipGetLastError();  // clear sticky error, fall back
    }
  }

  if (!done) {
    for (int t = 0; t < SEQ; t++) {
      const ushort* hp = (t & 1) ? hb1 : hb0;
      ushort*       hn = (t & 1) ? hb0 : hb1;
      if (fast) k_step<0><<<256, 256, 0, stream>>>(t, Xb, Wxb, Whb, bp, Ax, hp, hn, cst, out);
      else      k_step<1><<<256, 256, 0, stream>>>(t, Xb, Wxb, Whb, bp, Ax, hp, hn, cst, out);
    }
  }
}